// Round 2
// baseline (10029.719 us; speedup 1.0000x reference)
//
#include <hip/hip_runtime.h>
#include <stdint.h>

typedef __attribute__((ext_vector_type(8))) short short8;
typedef __attribute__((ext_vector_type(4))) float f32x4;
typedef unsigned int uint32;
typedef unsigned short ushort16;

#define SEQ 512
#define BATCH 128
#define DIN 512
#define DH 1024
#define DOUT 256

// ---- workspace layout (bytes) ----
#define XW_OFF   0u
#define XW_BYTES 134217728u            // 65536*1024*2 (bf16 xW)
#define WH_OFF   (XW_OFF + XW_BYTES)
#define WH_BYTES 2097152u              // 1024*1024 bf16 (N x K row-major)
#define WX_OFF   (WH_OFF + WH_BYTES)
#define WX_BYTES 1048576u              // 1024*512 bf16
#define HB_OFF   (WX_OFF + WX_BYTES)
#define HB_BYTES 524288u               // 2 x 128 x 512 dwords (bf16x2 h buffers)
#define DN_OFF   (HB_OFF + HB_BYTES)
#define DN_BYTES 262144u               // flags: 8 groups x 64 waves (zeroed region)

__device__ __forceinline__ ushort16 f2bf(float f) {
  uint32 u = __float_as_uint(f);
  u = u + 0x7fffu + ((u >> 16) & 1u);
  return (ushort16)(u >> 16);
}
__device__ __forceinline__ float bf2f(ushort16 h) {
  return __uint_as_float(((uint32)h) << 16);
}
__device__ __forceinline__ uint32 packbf(float lo, float hi) {
  return (uint32)f2bf(lo) | ((uint32)f2bf(hi) << 16);
}
__device__ __forceinline__ float tanh_fast(float x) {
  float e = __expf(2.0f * x);
  return 1.0f - 2.0f / (e + 1.0f);
}

// ---------------------------------------------------------------------------
// K0: convert weights to bf16, pack h0, zero flags
// ---------------------------------------------------------------------------
__global__ __launch_bounds__(256) void prep_kernel(
    const float* __restrict__ W_i2h, const float* __restrict__ hidden,
    ushort16* __restrict__ Wx, ushort16* __restrict__ Wh,
    uint32* __restrict__ hbuf, uint32* __restrict__ flags) {
  int idx = blockIdx.x * 256 + threadIdx.x;
  if (idx < DH * (DIN + DH)) {
    int row = idx / (DIN + DH);
    int col = idx - row * (DIN + DH);
    float v = W_i2h[idx];
    if (col < DIN) Wx[row * DIN + col] = f2bf(v);
    else           Wh[row * DH + (col - DIN)] = f2bf(v);
  }
  if (idx < BATCH * (DH / 2)) {        // 65536: pack h0 into buffer 0
    int b = idx >> 9, dk = idx & 511;
    hbuf[idx] = packbf(hidden[b * DH + dk * 2], hidden[b * DH + dk * 2 + 1]);
  }
  if (idx < 65536) flags[idx] = 0u;    // zero full flag region (re-poisoned 0xAA)
}

// ---------------------------------------------------------------------------
// K1: xW = x @ Wx^T  (M=65536, N=1024, K=512), bf16 in/out, fp32 accum
// ---------------------------------------------------------------------------
__global__ __launch_bounds__(256) void xw_gemm_kernel(
    const float* __restrict__ x, const ushort16* __restrict__ Wx,
    ushort16* __restrict__ xw) {
  __shared__ __attribute__((aligned(16))) ushort16 Al[128 * 72];
  __shared__ __attribute__((aligned(16))) ushort16 Bl[128 * 72];
  const int tid = threadIdx.x;
  const int lane = tid & 63;
  const int wv = tid >> 6;
  const int mh = wv & 1, nh = wv >> 1;
  const int bm = blockIdx.x >> 3;
  const int bn = blockIdx.x & 7;

  f32x4 acc[4][4];
#pragma unroll
  for (int i = 0; i < 4; ++i)
#pragma unroll
    for (int j = 0; j < 4; ++j) acc[i][j] = (f32x4){0.f, 0.f, 0.f, 0.f};

  uint32* Al32 = (uint32*)Al;

  for (int ko = 0; ko < DIN; ko += 64) {
#pragma unroll
    for (int i = 0; i < 8; ++i) {
      int linear = i * 256 + tid;
      int row = linear >> 4, c4 = linear & 15;
      const float4 v = *(const float4*)(x + (size_t)(bm * 128 + row) * DIN + ko + c4 * 4);
      uint2 p;
      p.x = packbf(v.x, v.y);
      p.y = packbf(v.z, v.w);
      *(uint2*)(Al32 + row * 36 + c4 * 2) = p;
    }
#pragma unroll
    for (int i = 0; i < 4; ++i) {
      int linear = i * 256 + tid;
      int row = linear >> 3, c8 = linear & 7;
      short8 v = *(const short8*)(Wx + (size_t)(bn * 128 + row) * DIN + ko + c8 * 8);
      *(short8*)(Bl + row * 72 + c8 * 8) = v;
    }
    __syncthreads();
#pragma unroll
    for (int kk = 0; kk < 64; kk += 32) {
      short8 af[4], bfv[4];
      const int kb = kk + ((lane >> 4) * 8);
#pragma unroll
      for (int mt = 0; mt < 4; ++mt)
        af[mt] = *(const short8*)(Al + (mh * 64 + mt * 16 + (lane & 15)) * 72 + kb);
#pragma unroll
      for (int nt = 0; nt < 4; ++nt)
        bfv[nt] = *(const short8*)(Bl + (nh * 64 + nt * 16 + (lane & 15)) * 72 + kb);
#pragma unroll
      for (int mt = 0; mt < 4; ++mt)
#pragma unroll
        for (int nt = 0; nt < 4; ++nt)
          acc[mt][nt] = __builtin_amdgcn_mfma_f32_16x16x32_bf16(af[mt], bfv[nt], acc[mt][nt], 0, 0, 0);
    }
    __syncthreads();
  }
#pragma unroll
  for (int mt = 0; mt < 4; ++mt)
#pragma unroll
    for (int nt = 0; nt < 4; ++nt)
#pragma unroll
      for (int r = 0; r < 4; ++r) {
        float v = acc[mt][nt][r];
        float o = __shfl_xor(v, 1);
        if (!(lane & 1)) {
          int m = bm * 128 + mh * 64 + mt * 16 + ((lane >> 4) * 4) + r;
          int c = bn * 128 + nh * 64 + nt * 16 + (lane & 15);
          ((uint32*)xw)[(size_t)m * 512 + (c >> 1)] = packbf(v, o);
        }
      }
}

// ---------------------------------------------------------------------------
// K2: recurrence. 128 blocks = 8 groups (blockIdx%8, XCD-local) x 16 blocks.
// Block: rows g*16..+16, cols w*64..+64. 4 waves, each owns one 16-col tile
// across FULL K=1024 (no K-split -> no reduction, one barrier/step).
// Sync: per-wave monotonic flags (release store of t), ballot-poll 64 flags.
// No atomic RMWs anywhere in the hot loop.
// ---------------------------------------------------------------------------
__global__ __launch_bounds__(256) void rnn_kernel(
    const ushort16* __restrict__ xw, const ushort16* __restrict__ Wh,
    const float* __restrict__ b_i2h,
    uint32* hbuf, uint32* flags, float* __restrict__ h_out) {
  const int g = blockIdx.x & 7;
  const int w = blockIdx.x >> 3;          // 0..15
  const int lane = threadIdx.x & 63;
  const int q = threadIdx.x >> 6;         // wave 0..3
  const int bcol = w * 64 + q * 16 + (lane & 15);
  const int rowloc = (lane >> 4) * 4;     // 0,4,8,12

  __shared__ __attribute__((aligned(16))) ushort16 h_lds[16 * 1032]; // stride 2064B

  // preload Wh: this wave's 16-col tile, full K. 128 VGPRs.
  short8 bfrag[32];
#pragma unroll
  for (int ks = 0; ks < 32; ++ks)
    bfrag[ks] = *(const short8*)(Wh + (size_t)bcol * DH + ks * 32 + ((lane >> 4) * 8));
  const float biasv = b_i2h[bcol];
  uint32* hl32 = (uint32*)h_lds;
  uint32* fgrp = flags + g * 64;
  const int myflag = w * 4 + q;

  for (int t = 1; t <= SEQ; ++t) {
    const int s = t - 1;
    // xW prefetch (independent of h; latency hides under the poll)
    float xwv[4];
#pragma unroll
    for (int r = 0; r < 4; ++r)
      xwv[r] = bf2f(xw[(size_t)(s * BATCH + g * 16 + rowloc + r) * DH + bcol]);

    // wait: all 64 waves of this group published h_{t-1} (flag >= t-1).
    // This also orders intra-block h_lds reuse (a wave's flag=t-1 implies its
    // MFMA reads of h_lds(t-1) are done), so one barrier/step suffices.
    if (t > 1) {
      const uint32 need = (uint32)(t - 1);
      for (;;) {
        uint32 v = __hip_atomic_load(fgrp + lane, __ATOMIC_RELAXED, __HIP_MEMORY_SCOPE_AGENT);
        if (__ballot(v >= need) == ~0ull) break;
      }
    }

    // stage h_{t-1} -> LDS: 16 rows x 512 dwords, 32 coalesced dwords/thread
    {
      uint32* hsrc = hbuf + ((s & 1) ? 65536 : 0);
#pragma unroll
      for (int j = 0; j < 32; ++j) {
        int linear = j * 256 + threadIdx.x;
        int row = linear >> 9, dk = linear & 511;
        uint32 vv = __hip_atomic_load(hsrc + (size_t)(g * 16 + row) * 512 + dk,
                                      __ATOMIC_RELAXED, __HIP_MEMORY_SCOPE_AGENT);
        hl32[row * 516 + dk] = vv;
      }
    }
    __syncthreads();

    // h @ Wh for this wave's 16-col tile, full K=1024
    f32x4 acc = (f32x4){0.f, 0.f, 0.f, 0.f};
#pragma unroll
    for (int ks = 0; ks < 32; ++ks) {
      short8 af = *(const short8*)((const char*)h_lds +
                   (lane & 15) * 2064 + ks * 64 + ((lane >> 4) * 16));
      acc = __builtin_amdgcn_mfma_f32_16x16x32_bf16(af, bfrag[ks], acc, 0, 0, 0);
    }

    float hv[4];
#pragma unroll
    for (int r = 0; r < 4; ++r)
      hv[r] = tanh_fast(acc[r] + biasv + xwv[r]);

    // publish h_t (packed bf16x2, agent scope), then per-wave flag (release)
    uint32* hdst = hbuf + ((t & 1) ? 65536 : 0);
#pragma unroll
    for (int r = 0; r < 4; ++r) {
      float o = __shfl_xor(hv[r], 1);
      if (!(lane & 1)) {
        int b = g * 16 + rowloc + r;
        __hip_atomic_store(hdst + (size_t)b * 512 + (bcol >> 1), packbf(hv[r], o),
                           __ATOMIC_RELAXED, __HIP_MEMORY_SCOPE_AGENT);
      }
    }
    if (t == SEQ) {
#pragma unroll
      for (int r = 0; r < 4; ++r)
        h_out[(size_t)(g * 16 + rowloc + r) * DH + bcol] = hv[r];
    }
    if (lane == 0)
      __hip_atomic_store(fgrp + myflag, (uint32)t,
                         __ATOMIC_RELEASE, __HIP_MEMORY_SCOPE_AGENT);
  }
}

// ---------------------------------------------------------------------------
// K3: logits = h_final @ W_h2o^T + b; row softmax. 1 block per batch row.
// ---------------------------------------------------------------------------
__global__ __launch_bounds__(256) void head_kernel(
    const float* __restrict__ hfin, const float* __restrict__ W,
    const float* __restrict__ bias, float* __restrict__ out) {
  __shared__ __attribute__((aligned(16))) float hrow[DH];
  __shared__ float rbuf[256];
  const int b = blockIdx.x;
  const int tid = threadIdx.x;
  for (int i = tid; i < DH; i += 256) hrow[i] = hfin[(size_t)b * DH + i];
  __syncthreads();
  float s = bias[tid];
  const float4* wr = (const float4*)(W + (size_t)tid * DH);
#pragma unroll 4
  for (int k = 0; k < DH / 4; ++k) {
    float4 wv = wr[k];
    float4 hv = *(const float4*)(hrow + k * 4);
    s += wv.x * hv.x + wv.y * hv.y + wv.z * hv.z + wv.w * hv.w;
  }
  rbuf[tid] = s;
  __syncthreads();
  for (int off = 128; off > 0; off >>= 1) {
    if (tid < off) rbuf[tid] = fmaxf(rbuf[tid], rbuf[tid + off]);
    __syncthreads();
  }
  float mx = rbuf[0];
  __syncthreads();
  float e = __expf(s - mx);
  rbuf[tid] = e;
  __syncthreads();
  for (int off = 128; off > 0; off >>= 1) {
    if (tid < off) rbuf[tid] += rbuf[tid + off];
    __syncthreads();
  }
  out[(size_t)b * DOUT + tid] = e / rbuf[0];
}

// ---------------------------------------------------------------------------
extern "C" void kernel_launch(void* const* d_in, const int* in_sizes, int n_in,
                              void* d_out, int out_size, void* d_ws, size_t ws_size,
                              hipStream_t stream) {
  const float* x      = (const float*)d_in[0];
  const float* hidden = (const float*)d_in[1];
  const float* W_i2h  = (const float*)d_in[2];
  const float* b_i2h  = (const float*)d_in[3];
  const float* W_h2o  = (const float*)d_in[4];
  const float* b_h2o  = (const float*)d_in[5];
  float* out = (float*)d_out;

  char* ws = (char*)d_ws;
  ushort16* xw    = (ushort16*)(ws + XW_OFF);
  ushort16* Wh    = (ushort16*)(ws + WH_OFF);
  ushort16* Wx    = (ushort16*)(ws + WX_OFF);
  uint32*   hbuf  = (uint32*)(ws + HB_OFF);
  uint32*   flags = (uint32*)(ws + DN_OFF);

  prep_kernel<<<6144, 256, 0, stream>>>(W_i2h, hidden, Wx, Wh, hbuf, flags);
  xw_gemm_kernel<<<4096, 256, 0, stream>>>(x, Wx, xw);
  rnn_kernel<<<128, 256, 0, stream>>>(xw, Wh, b_i2h, hbuf, flags, out + BATCH * DOUT);
  head_kernel<<<128, 256, 0, stream>>>(out + BATCH * DOUT, W_h2o, b_h2o, out);
}

// Round 3
// 2947.528 us; speedup vs baseline: 3.4028x; 3.4028x over previous
//
#include <hip/hip_runtime.h>
#include <stdint.h>

typedef __attribute__((ext_vector_type(8))) short short8;
typedef __attribute__((ext_vector_type(4))) float f32x4;
typedef __attribute__((ext_vector_type(4))) unsigned int uint32x4;
typedef unsigned int uint32;
typedef unsigned short ushort16;

#define SEQ 512
#define BATCH 128
#define DIN 512
#define DH 1024
#define DOUT 256

// ---- workspace layout (bytes) ----
#define XW_OFF   0u
#define XW_BYTES 134217728u            // 65536*1024*2 (bf16 xW)
#define WH_OFF   (XW_OFF + XW_BYTES)
#define WH_BYTES 2097152u              // 1024*1024 bf16 (N x K row-major)
#define WX_OFF   (WH_OFF + WH_BYTES)
#define WX_BYTES 1048576u              // 1024*512 bf16
#define HB_OFF   (WX_OFF + WX_BYTES)
#define HB_BYTES 524288u               // 2 x 128 x 512 dwords (bf16x2 h buffers)
#define DN_OFF   (HB_OFF + HB_BYTES)
#define DN_BYTES 262144u               // flags: 8 groups x 64 waves

__device__ __forceinline__ ushort16 f2bf(float f) {
  uint32 u = __float_as_uint(f);
  u = u + 0x7fffu + ((u >> 16) & 1u);
  return (ushort16)(u >> 16);
}
__device__ __forceinline__ float bf2f(ushort16 h) {
  return __uint_as_float(((uint32)h) << 16);
}
__device__ __forceinline__ uint32 packbf(float lo, float hi) {
  return (uint32)f2bf(lo) | ((uint32)f2bf(hi) << 16);
}
__device__ __forceinline__ float tanh_fast(float x) {
  float e = __expf(2.0f * x);
  return 1.0f - 2.0f / (e + 1.0f);
}

// ---------------------------------------------------------------------------
// K0: convert weights to bf16, pack h0, zero flags
// ---------------------------------------------------------------------------
__global__ __launch_bounds__(256) void prep_kernel(
    const float* __restrict__ W_i2h, const float* __restrict__ hidden,
    ushort16* __restrict__ Wx, ushort16* __restrict__ Wh,
    uint32* __restrict__ hbuf, uint32* __restrict__ flags) {
  int idx = blockIdx.x * 256 + threadIdx.x;
  if (idx < DH * (DIN + DH)) {
    int row = idx / (DIN + DH);
    int col = idx - row * (DIN + DH);
    float v = W_i2h[idx];
    if (col < DIN) Wx[row * DIN + col] = f2bf(v);
    else           Wh[row * DH + (col - DIN)] = f2bf(v);
  }
  if (idx < BATCH * (DH / 2)) {        // 65536: pack h0 into buffer 0
    int b = idx >> 9, dk = idx & 511;
    hbuf[idx] = packbf(hidden[b * DH + dk * 2], hidden[b * DH + dk * 2 + 1]);
  }
  if (idx < 65536) flags[idx] = 0u;
}

// ---------------------------------------------------------------------------
// K1: xW = x @ Wx^T  (M=65536, N=1024, K=512), bf16 in/out, fp32 accum
// ---------------------------------------------------------------------------
__global__ __launch_bounds__(256) void xw_gemm_kernel(
    const float* __restrict__ x, const ushort16* __restrict__ Wx,
    ushort16* __restrict__ xw) {
  __shared__ __attribute__((aligned(16))) ushort16 Al[128 * 72];
  __shared__ __attribute__((aligned(16))) ushort16 Bl[128 * 72];
  const int tid = threadIdx.x;
  const int lane = tid & 63;
  const int wv = tid >> 6;
  const int mh = wv & 1, nh = wv >> 1;
  const int bm = blockIdx.x >> 3;
  const int bn = blockIdx.x & 7;

  f32x4 acc[4][4];
#pragma unroll
  for (int i = 0; i < 4; ++i)
#pragma unroll
    for (int j = 0; j < 4; ++j) acc[i][j] = (f32x4){0.f, 0.f, 0.f, 0.f};

  uint32* Al32 = (uint32*)Al;

  for (int ko = 0; ko < DIN; ko += 64) {
#pragma unroll
    for (int i = 0; i < 8; ++i) {
      int linear = i * 256 + tid;
      int row = linear >> 4, c4 = linear & 15;
      const float4 v = *(const float4*)(x + (size_t)(bm * 128 + row) * DIN + ko + c4 * 4);
      uint2 p;
      p.x = packbf(v.x, v.y);
      p.y = packbf(v.z, v.w);
      *(uint2*)(Al32 + row * 36 + c4 * 2) = p;
    }
#pragma unroll
    for (int i = 0; i < 4; ++i) {
      int linear = i * 256 + tid;
      int row = linear >> 3, c8 = linear & 7;
      short8 v = *(const short8*)(Wx + (size_t)(bn * 128 + row) * DIN + ko + c8 * 8);
      *(short8*)(Bl + row * 72 + c8 * 8) = v;
    }
    __syncthreads();
#pragma unroll
    for (int kk = 0; kk < 64; kk += 32) {
      short8 af[4], bfv[4];
      const int kb = kk + ((lane >> 4) * 8);
#pragma unroll
      for (int mt = 0; mt < 4; ++mt)
        af[mt] = *(const short8*)(Al + (mh * 64 + mt * 16 + (lane & 15)) * 72 + kb);
#pragma unroll
      for (int nt = 0; nt < 4; ++nt)
        bfv[nt] = *(const short8*)(Bl + (nh * 64 + nt * 16 + (lane & 15)) * 72 + kb);
#pragma unroll
      for (int mt = 0; mt < 4; ++mt)
#pragma unroll
        for (int nt = 0; nt < 4; ++nt)
          acc[mt][nt] = __builtin_amdgcn_mfma_f32_16x16x32_bf16(af[mt], bfv[nt], acc[mt][nt], 0, 0, 0);
    }
    __syncthreads();
  }
#pragma unroll
  for (int mt = 0; mt < 4; ++mt)
#pragma unroll
    for (int nt = 0; nt < 4; ++nt)
#pragma unroll
      for (int r = 0; r < 4; ++r) {
        float v = acc[mt][nt][r];
        float o = __shfl_xor(v, 1);
        if (!(lane & 1)) {
          int m = bm * 128 + mh * 64 + mt * 16 + ((lane >> 4) * 4) + r;
          int c = bn * 128 + nh * 64 + nt * 16 + (lane & 15);
          ((uint32*)xw)[(size_t)m * 512 + (c >> 1)] = packbf(v, o);
        }
      }
}

// ---------------------------------------------------------------------------
// K2: recurrence. 128 blocks = 8 groups (blockIdx%8) x 16 blocks.
// Wave owns 16 cols x full K=1024; Wh resident in 128 VGPRs
// (__launch_bounds__(256,1) lifts the default 128-VGPR occupancy cap that
// silently spilled it in rounds 1-2). Staging: one batched asm block of
// 8 x global_load_dwordx4 sc0 sc1 (single MALL round-trip). Publishes:
// asm sc0 sc1 stores + explicit vmcnt(0) drain + release flag.
// ---------------------------------------------------------------------------
__global__ __launch_bounds__(256, 1) void rnn_kernel(
    const ushort16* __restrict__ xw, const ushort16* __restrict__ Wh,
    const float* __restrict__ b_i2h,
    uint32* hbuf, uint32* flags, float* __restrict__ h_out) {
  const int g = blockIdx.x & 7;
  const int w = blockIdx.x >> 3;          // 0..15
  const int tid = threadIdx.x;
  const int lane = tid & 63;
  const int q = tid >> 6;                 // wave 0..3
  const int bcol = w * 64 + q * 16 + (lane & 15);
  const int rowloc = (lane >> 4) * 4;     // 0,4,8,12

  __shared__ __attribute__((aligned(16))) ushort16 h_lds[16 * 1032]; // row stride 2064B

  // Wh fragments: this wave's 16-col tile, full K. 128 VGPRs, loop-invariant.
  short8 bfrag[32];
#pragma unroll
  for (int ks = 0; ks < 32; ++ks)
    bfrag[ks] = *(const short8*)(Wh + (size_t)bcol * DH + ks * 32 + ((lane >> 4) * 8));
  const float biasv = b_i2h[bcol];
  uint32* hl32 = (uint32*)h_lds;
  uint32* fgrp = flags + g * 64;
  const int myflag = w * 4 + q;

  // staging addresses: thread covers 16B chunks c = tid + 256*j, j=0..7
  // row = c>>7 (0..15), col16 = c&127; global byte off = row*2048 + col16*16
  const int r0 = tid >> 7;                // 0 or 1
  const int c16 = (tid & 127) * 16;
  uint32 voff[8];
#pragma unroll
  for (int j = 0; j < 8; ++j) voff[j] = (uint32)((r0 + 2 * j) * 2048 + c16);
  const uint32* hgrp0 = hbuf + (size_t)g * 16 * 512;           // buffer 0 group base
  const uint32* hgrp1 = hbuf + 65536 + (size_t)g * 16 * 512;   // buffer 1 group base

  for (int t = 1; t <= SEQ; ++t) {
    const int s = t - 1;
    // xW prefetch (independent of h; overlaps the poll)
    float xwv[4];
#pragma unroll
    for (int r = 0; r < 4; ++r)
      xwv[r] = bf2f(xw[(size_t)(s * BATCH + g * 16 + rowloc + r) * DH + bcol]);

    // wait: all 64 waves of this group published h_{t-1}
    if (t > 1) {
      const uint32 need = (uint32)(t - 1);
      for (;;) {
        uint32 v = __hip_atomic_load(fgrp + lane, __ATOMIC_RELAXED, __HIP_MEMORY_SCOPE_AGENT);
        if (__ballot(v >= need) == ~0ull) break;
      }
    }

    // stage h_{t-1} -> LDS: 8 x dwordx4, one round-trip, L1/L2-bypassing
    {
      const uint32* hsrc = (s & 1) ? hgrp1 : hgrp0;
      uint32x4 rb[8];
      asm volatile(
          "global_load_dwordx4 %0, %8, %16 sc0 sc1\n\t"
          "global_load_dwordx4 %1, %9, %16 sc0 sc1\n\t"
          "global_load_dwordx4 %2, %10, %16 sc0 sc1\n\t"
          "global_load_dwordx4 %3, %11, %16 sc0 sc1\n\t"
          "global_load_dwordx4 %4, %12, %16 sc0 sc1\n\t"
          "global_load_dwordx4 %5, %13, %16 sc0 sc1\n\t"
          "global_load_dwordx4 %6, %14, %16 sc0 sc1\n\t"
          "global_load_dwordx4 %7, %15, %16 sc0 sc1\n\t"
          "s_waitcnt vmcnt(0)"
          : "=&v"(rb[0]), "=&v"(rb[1]), "=&v"(rb[2]), "=&v"(rb[3]),
            "=&v"(rb[4]), "=&v"(rb[5]), "=&v"(rb[6]), "=&v"(rb[7])
          : "v"(voff[0]), "v"(voff[1]), "v"(voff[2]), "v"(voff[3]),
            "v"(voff[4]), "v"(voff[5]), "v"(voff[6]), "v"(voff[7]),
            "s"(hsrc)
          : "memory");
#pragma unroll
      for (int j = 0; j < 8; ++j)
        *(uint32x4*)(hl32 + (size_t)(r0 + 2 * j) * 516 + (tid & 127) * 4) = rb[j];
    }
    __syncthreads();

    // h @ Wh for this wave's 16-col tile, full K=1024
    f32x4 acc = (f32x4){0.f, 0.f, 0.f, 0.f};
#pragma unroll
    for (int ks = 0; ks < 32; ++ks) {
      short8 af = *(const short8*)((const char*)h_lds +
                   (lane & 15) * 2064 + ks * 64 + ((lane >> 4) * 16));
      acc = __builtin_amdgcn_mfma_f32_16x16x32_bf16(af, bfrag[ks], acc, 0, 0, 0);
    }

    float hv[4];
#pragma unroll
    for (int r = 0; r < 4; ++r)
      hv[r] = tanh_fast(acc[r] + biasv + xwv[r]);

    // publish h_t (packed bf16x2, write-through to MALL)
    {
      uint32* hdst = (uint32*)((t & 1) ? hgrp1 : hgrp0);
#pragma unroll
      for (int r = 0; r < 4; ++r) {
        float o = __shfl_xor(hv[r], 1);
        uint32 pk = packbf(hv[r], o);
        if (!(lane & 1)) {
          uint32* p = hdst + (size_t)(rowloc + r) * 512 + (bcol >> 1);
          asm volatile("global_store_dword %0, %1, off sc0 sc1"
                       :: "v"(p), "v"(pk) : "memory");
        }
      }
    }
    if (t == SEQ) {
#pragma unroll
      for (int r = 0; r < 4; ++r)
        h_out[(size_t)(g * 16 + rowloc + r) * DH + bcol] = hv[r];
    }
    // drain publishes, then release flag
    asm volatile("s_waitcnt vmcnt(0)" ::: "memory");
    if (lane == 0) {
      uint32* fp = fgrp + myflag;
      uint32 tv = (uint32)t;
      asm volatile("global_store_dword %0, %1, off sc0 sc1"
                   :: "v"(fp), "v"(tv) : "memory");
    }
  }
}

// ---------------------------------------------------------------------------
// K3: logits = h_final @ W_h2o^T + b; row softmax. 1 block per batch row.
// ---------------------------------------------------------------------------
__global__ __launch_bounds__(256) void head_kernel(
    const float* __restrict__ hfin, const float* __restrict__ W,
    const float* __restrict__ bias, float* __restrict__ out) {
  __shared__ __attribute__((aligned(16))) float hrow[DH];
  __shared__ float rbuf[256];
  const int b = blockIdx.x;
  const int tid = threadIdx.x;
  for (int i = tid; i < DH; i += 256) hrow[i] = hfin[(size_t)b * DH + i];
  __syncthreads();
  float s = bias[tid];
  const float4* wr = (const float4*)(W + (size_t)tid * DH);
#pragma unroll 4
  for (int k = 0; k < DH / 4; ++k) {
    float4 wv = wr[k];
    float4 hv = *(const float4*)(hrow + k * 4);
    s += wv.x * hv.x + wv.y * hv.y + wv.z * hv.z + wv.w * hv.w;
  }
  rbuf[tid] = s;
  __syncthreads();
  for (int off = 128; off > 0; off >>= 1) {
    if (tid < off) rbuf[tid] = fmaxf(rbuf[tid], rbuf[tid + off]);
    __syncthreads();
  }
  float mx = rbuf[0];
  __syncthreads();
  float e = __expf(s - mx);
  rbuf[tid] = e;
  __syncthreads();
  for (int off = 128; off > 0; off >>= 1) {
    if (tid < off) rbuf[tid] += rbuf[tid + off];
    __syncthreads();
  }
  out[(size_t)b * DOUT + tid] = e / rbuf[0];
}

// ---------------------------------------------------------------------------
extern "C" void kernel_launch(void* const* d_in, const int* in_sizes, int n_in,
                              void* d_out, int out_size, void* d_ws, size_t ws_size,
                              hipStream_t stream) {
  const float* x      = (const float*)d_in[0];
  const float* hidden = (const float*)d_in[1];
  const float* W_i2h  = (const float*)d_in[2];
  const float* b_i2h  = (const float*)d_in[3];
  const float* W_h2o  = (const float*)d_in[4];
  const float* b_h2o  = (const float*)d_in[5];
  float* out = (float*)d_out;

  char* ws = (char*)d_ws;
  ushort16* xw    = (ushort16*)(ws + XW_OFF);
  ushort16* Wh    = (ushort16*)(ws + WH_OFF);
  ushort16* Wx    = (ushort16*)(ws + WX_OFF);
  uint32*   hbuf  = (uint32*)(ws + HB_OFF);
  uint32*   flags = (uint32*)(ws + DN_OFF);

  prep_kernel<<<6144, 256, 0, stream>>>(W_i2h, hidden, Wx, Wh, hbuf, flags);
  xw_gemm_kernel<<<4096, 256, 0, stream>>>(x, Wx, xw);
  rnn_kernel<<<128, 256, 0, stream>>>(xw, Wh, b_i2h, hbuf, flags, out + BATCH * DOUT);
  head_kernel<<<128, 256, 0, stream>>>(out + BATCH * DOUT, W_h2o, b_h2o, out);
}

// Round 4
// 2164.092 us; speedup vs baseline: 4.6346x; 1.3620x over previous
//
#include <hip/hip_runtime.h>
#include <stdint.h>

typedef __attribute__((ext_vector_type(8))) short short8;
typedef __attribute__((ext_vector_type(4))) float f32x4;
typedef __attribute__((ext_vector_type(4))) unsigned int uint32x4;
typedef unsigned int uint32;
typedef unsigned short ushort16;

#define SEQ 512
#define BATCH 128
#define DIN 512
#define DH 1024
#define DOUT 256

// ---- workspace layout (bytes) ----
#define XW_OFF   0u
#define XW_BYTES 134217728u            // 65536*1024*2 (bf16 xW)
#define WH_OFF   (XW_OFF + XW_BYTES)
#define WH_BYTES 2097152u              // 1024*1024 bf16 (N x K row-major)
#define WX_OFF   (WH_OFF + WH_BYTES)
#define WX_BYTES 1048576u              // 1024*512 bf16
#define HB_OFF   (WX_OFF + WX_BYTES)
#define HB_BYTES 524288u               // 2 x 128 x 512 dwords (bf16x2 h buffers)
#define DN_OFF   (HB_OFF + HB_BYTES)
#define DN_BYTES 262144u               // flags: 8 groups x 64 waves

__device__ __forceinline__ ushort16 f2bf(float f) {
  uint32 u = __float_as_uint(f);
  u = u + 0x7fffu + ((u >> 16) & 1u);
  return (ushort16)(u >> 16);
}
__device__ __forceinline__ float bf2f(ushort16 h) {
  return __uint_as_float(((uint32)h) << 16);
}
__device__ __forceinline__ uint32 packbf(float lo, float hi) {
  return (uint32)f2bf(lo) | ((uint32)f2bf(hi) << 16);
}
__device__ __forceinline__ float tanh_fast(float x) {
  float e = __expf(2.0f * x);
  return 1.0f - 2.0f / (e + 1.0f);
}

// ---------------------------------------------------------------------------
// K0: convert weights to bf16, pack h0, zero flags
// ---------------------------------------------------------------------------
__global__ __launch_bounds__(256) void prep_kernel(
    const float* __restrict__ W_i2h, const float* __restrict__ hidden,
    ushort16* __restrict__ Wx, ushort16* __restrict__ Wh,
    uint32* __restrict__ hbuf, uint32* __restrict__ flags) {
  int idx = blockIdx.x * 256 + threadIdx.x;
  if (idx < DH * (DIN + DH)) {
    int row = idx / (DIN + DH);
    int col = idx - row * (DIN + DH);
    float v = W_i2h[idx];
    if (col < DIN) Wx[row * DIN + col] = f2bf(v);
    else           Wh[row * DH + (col - DIN)] = f2bf(v);
  }
  if (idx < BATCH * (DH / 2)) {        // 65536: pack h0 into buffer 0
    int b = idx >> 9, dk = idx & 511;
    hbuf[idx] = packbf(hidden[b * DH + dk * 2], hidden[b * DH + dk * 2 + 1]);
  }
  if (idx < 65536) flags[idx] = 0u;
}

// ---------------------------------------------------------------------------
// K1: xW = x @ Wx^T  (M=65536, N=1024, K=512), bf16 in/out, fp32 accum
// ---------------------------------------------------------------------------
__global__ __launch_bounds__(256) void xw_gemm_kernel(
    const float* __restrict__ x, const ushort16* __restrict__ Wx,
    ushort16* __restrict__ xw) {
  __shared__ __attribute__((aligned(16))) ushort16 Al[128 * 72];
  __shared__ __attribute__((aligned(16))) ushort16 Bl[128 * 72];
  const int tid = threadIdx.x;
  const int lane = tid & 63;
  const int wv = tid >> 6;
  const int mh = wv & 1, nh = wv >> 1;
  const int bm = blockIdx.x >> 3;
  const int bn = blockIdx.x & 7;

  f32x4 acc[4][4];
#pragma unroll
  for (int i = 0; i < 4; ++i)
#pragma unroll
    for (int j = 0; j < 4; ++j) acc[i][j] = (f32x4){0.f, 0.f, 0.f, 0.f};

  uint32* Al32 = (uint32*)Al;

  for (int ko = 0; ko < DIN; ko += 64) {
#pragma unroll
    for (int i = 0; i < 8; ++i) {
      int linear = i * 256 + tid;
      int row = linear >> 4, c4 = linear & 15;
      const float4 v = *(const float4*)(x + (size_t)(bm * 128 + row) * DIN + ko + c4 * 4);
      uint2 p;
      p.x = packbf(v.x, v.y);
      p.y = packbf(v.z, v.w);
      *(uint2*)(Al32 + row * 36 + c4 * 2) = p;
    }
#pragma unroll
    for (int i = 0; i < 4; ++i) {
      int linear = i * 256 + tid;
      int row = linear >> 3, c8 = linear & 7;
      short8 v = *(const short8*)(Wx + (size_t)(bn * 128 + row) * DIN + ko + c8 * 8);
      *(short8*)(Bl + row * 72 + c8 * 8) = v;
    }
    __syncthreads();
#pragma unroll
    for (int kk = 0; kk < 64; kk += 32) {
      short8 af[4], bfv[4];
      const int kb = kk + ((lane >> 4) * 8);
#pragma unroll
      for (int mt = 0; mt < 4; ++mt)
        af[mt] = *(const short8*)(Al + (mh * 64 + mt * 16 + (lane & 15)) * 72 + kb);
#pragma unroll
      for (int nt = 0; nt < 4; ++nt)
        bfv[nt] = *(const short8*)(Bl + (nh * 64 + nt * 16 + (lane & 15)) * 72 + kb);
#pragma unroll
      for (int mt = 0; mt < 4; ++mt)
#pragma unroll
        for (int nt = 0; nt < 4; ++nt)
          acc[mt][nt] = __builtin_amdgcn_mfma_f32_16x16x32_bf16(af[mt], bfv[nt], acc[mt][nt], 0, 0, 0);
    }
    __syncthreads();
  }
#pragma unroll
  for (int mt = 0; mt < 4; ++mt)
#pragma unroll
    for (int nt = 0; nt < 4; ++nt)
#pragma unroll
      for (int r = 0; r < 4; ++r) {
        float v = acc[mt][nt][r];
        float o = __shfl_xor(v, 1);
        if (!(lane & 1)) {
          int m = bm * 128 + mh * 64 + mt * 16 + ((lane >> 4) * 4) + r;
          int c = bn * 128 + nh * 64 + nt * 16 + (lane & 15);
          ((uint32*)xw)[(size_t)m * 512 + (c >> 1)] = packbf(v, o);
        }
      }
}

// ---------------------------------------------------------------------------
// K2: recurrence. 128 blocks = 8 groups (blockIdx%8) x 16 blocks.
// Wave owns 16 cols x full K=1024. Wh fragments PINNED in registers via an
// empty "+v" asm inside the loop (round 3 showed the compiler otherwise
// re-loads them from L2 every step: VGPR_Count was 104 < 128 needed).
// Staging: one batched asm block of 8 x global_load_dwordx4 sc0 sc1.
// ---------------------------------------------------------------------------
__global__ __launch_bounds__(256, 1) void rnn_kernel(
    const ushort16* __restrict__ xw, const ushort16* __restrict__ Wh,
    const float* __restrict__ b_i2h,
    uint32* hbuf, uint32* flags, float* __restrict__ h_out) {
  const int g = blockIdx.x & 7;
  const int w = blockIdx.x >> 3;          // 0..15
  const int tid = threadIdx.x;
  const int lane = tid & 63;
  const int q = tid >> 6;                 // wave 0..3
  const int bcol = w * 64 + q * 16 + (lane & 15);
  const int rowloc = (lane >> 4) * 4;     // 0,4,8,12

  __shared__ __attribute__((aligned(16))) ushort16 h_lds[16 * 1032]; // row stride 2064B

  // Wh fragments: this wave's 16-col tile, full K. 128 VGPRs, loop-invariant.
  short8 bfrag[32];
#pragma unroll
  for (int ks = 0; ks < 32; ++ks)
    bfrag[ks] = *(const short8*)(Wh + (size_t)bcol * DH + ks * 32 + ((lane >> 4) * 8));
  const float biasv = b_i2h[bcol];
  uint32* hl32 = (uint32*)h_lds;
  uint32* fgrp = flags + g * 64;
  const int myflag = w * 4 + q;

  // staging addresses: thread covers 16B chunks c = tid + 256*j, j=0..7
  const int r0 = tid >> 7;                // 0 or 1
  const int c16 = (tid & 127) * 16;
  uint32 voff[8];
#pragma unroll
  for (int j = 0; j < 8; ++j) voff[j] = (uint32)((r0 + 2 * j) * 2048 + c16);
  const uint32* hgrp0 = hbuf + (size_t)g * 16 * 512;           // buffer 0 group base
  const uint32* hgrp1 = hbuf + 65536 + (size_t)g * 16 * 512;   // buffer 1 group base

  for (int t = 1; t <= SEQ; ++t) {
    const int s = t - 1;
    // PIN: force all 32 Wh fragments to stay register-resident across the
    // loop. Empty asm "redefines" them -> loads cannot be rematerialized.
    asm volatile("" : "+v"(bfrag[0]), "+v"(bfrag[1]), "+v"(bfrag[2]), "+v"(bfrag[3]),
                      "+v"(bfrag[4]), "+v"(bfrag[5]), "+v"(bfrag[6]), "+v"(bfrag[7]),
                      "+v"(bfrag[8]), "+v"(bfrag[9]), "+v"(bfrag[10]), "+v"(bfrag[11]),
                      "+v"(bfrag[12]), "+v"(bfrag[13]), "+v"(bfrag[14]), "+v"(bfrag[15]));
    asm volatile("" : "+v"(bfrag[16]), "+v"(bfrag[17]), "+v"(bfrag[18]), "+v"(bfrag[19]),
                      "+v"(bfrag[20]), "+v"(bfrag[21]), "+v"(bfrag[22]), "+v"(bfrag[23]),
                      "+v"(bfrag[24]), "+v"(bfrag[25]), "+v"(bfrag[26]), "+v"(bfrag[27]),
                      "+v"(bfrag[28]), "+v"(bfrag[29]), "+v"(bfrag[30]), "+v"(bfrag[31]));

    // xW prefetch (independent of h; overlaps the poll)
    float xwv[4];
#pragma unroll
    for (int r = 0; r < 4; ++r)
      xwv[r] = bf2f(xw[(size_t)(s * BATCH + g * 16 + rowloc + r) * DH + bcol]);

    // wait: all 64 waves of this group published h_{t-1}
    if (t > 1) {
      const uint32 need = (uint32)(t - 1);
      for (;;) {
        uint32 v = __hip_atomic_load(fgrp + lane, __ATOMIC_RELAXED, __HIP_MEMORY_SCOPE_AGENT);
        if (__ballot(v >= need) == ~0ull) break;
      }
    }

    // stage h_{t-1} -> LDS: 8 x dwordx4, one round-trip, L1/L2-bypassing
    {
      const uint32* hsrc = (s & 1) ? hgrp1 : hgrp0;
      uint32x4 rb[8];
      asm volatile(
          "global_load_dwordx4 %0, %8, %16 sc0 sc1\n\t"
          "global_load_dwordx4 %1, %9, %16 sc0 sc1\n\t"
          "global_load_dwordx4 %2, %10, %16 sc0 sc1\n\t"
          "global_load_dwordx4 %3, %11, %16 sc0 sc1\n\t"
          "global_load_dwordx4 %4, %12, %16 sc0 sc1\n\t"
          "global_load_dwordx4 %5, %13, %16 sc0 sc1\n\t"
          "global_load_dwordx4 %6, %14, %16 sc0 sc1\n\t"
          "global_load_dwordx4 %7, %15, %16 sc0 sc1\n\t"
          "s_waitcnt vmcnt(0)"
          : "=&v"(rb[0]), "=&v"(rb[1]), "=&v"(rb[2]), "=&v"(rb[3]),
            "=&v"(rb[4]), "=&v"(rb[5]), "=&v"(rb[6]), "=&v"(rb[7])
          : "v"(voff[0]), "v"(voff[1]), "v"(voff[2]), "v"(voff[3]),
            "v"(voff[4]), "v"(voff[5]), "v"(voff[6]), "v"(voff[7]),
            "s"(hsrc)
          : "memory");
#pragma unroll
      for (int j = 0; j < 8; ++j)
        *(uint32x4*)(hl32 + (size_t)(r0 + 2 * j) * 516 + (tid & 127) * 4) = rb[j];
    }
    __syncthreads();

    // h @ Wh, full K=1024; two independent accumulator chains (halved dep latency)
    f32x4 acc0 = (f32x4){0.f, 0.f, 0.f, 0.f};
    f32x4 acc1 = (f32x4){0.f, 0.f, 0.f, 0.f};
#pragma unroll
    for (int ks = 0; ks < 16; ++ks) {
      short8 af0 = *(const short8*)((const char*)h_lds +
                    (lane & 15) * 2064 + (2 * ks) * 64 + ((lane >> 4) * 16));
      short8 af1 = *(const short8*)((const char*)h_lds +
                    (lane & 15) * 2064 + (2 * ks + 1) * 64 + ((lane >> 4) * 16));
      acc0 = __builtin_amdgcn_mfma_f32_16x16x32_bf16(af0, bfrag[2 * ks], acc0, 0, 0, 0);
      acc1 = __builtin_amdgcn_mfma_f32_16x16x32_bf16(af1, bfrag[2 * ks + 1], acc1, 0, 0, 0);
    }

    float hv[4];
#pragma unroll
    for (int r = 0; r < 4; ++r)
      hv[r] = tanh_fast(acc0[r] + acc1[r] + biasv + xwv[r]);

    // publish h_t (packed bf16x2, write-through to MALL)
    {
      uint32* hdst = (uint32*)((t & 1) ? hgrp1 : hgrp0);
#pragma unroll
      for (int r = 0; r < 4; ++r) {
        float o = __shfl_xor(hv[r], 1);
        uint32 pk = packbf(hv[r], o);
        if (!(lane & 1)) {
          uint32* p = hdst + (size_t)(rowloc + r) * 512 + (bcol >> 1);
          asm volatile("global_store_dword %0, %1, off sc0 sc1"
                       :: "v"(p), "v"(pk) : "memory");
        }
      }
    }
    if (t == SEQ) {
#pragma unroll
      for (int r = 0; r < 4; ++r)
        h_out[(size_t)(g * 16 + rowloc + r) * DH + bcol] = hv[r];
    }
    // drain publishes, then release flag
    asm volatile("s_waitcnt vmcnt(0)" ::: "memory");
    if (lane == 0) {
      uint32* fp = fgrp + myflag;
      uint32 tv = (uint32)t;
      asm volatile("global_store_dword %0, %1, off sc0 sc1"
                   :: "v"(fp), "v"(tv) : "memory");
    }
  }
}

// ---------------------------------------------------------------------------
// K3: logits = h_final @ W_h2o^T + b; row softmax. 1 block per batch row.
// ---------------------------------------------------------------------------
__global__ __launch_bounds__(256) void head_kernel(
    const float* __restrict__ hfin, const float* __restrict__ W,
    const float* __restrict__ bias, float* __restrict__ out) {
  __shared__ __attribute__((aligned(16))) float hrow[DH];
  __shared__ float rbuf[256];
  const int b = blockIdx.x;
  const int tid = threadIdx.x;
  for (int i = tid; i < DH; i += 256) hrow[i] = hfin[(size_t)b * DH + i];
  __syncthreads();
  float s = bias[tid];
  const float4* wr = (const float4*)(W + (size_t)tid * DH);
#pragma unroll 4
  for (int k = 0; k < DH / 4; ++k) {
    float4 wv = wr[k];
    float4 hv = *(const float4*)(hrow + k * 4);
    s += wv.x * hv.x + wv.y * hv.y + wv.z * hv.z + wv.w * hv.w;
  }
  rbuf[tid] = s;
  __syncthreads();
  for (int off = 128; off > 0; off >>= 1) {
    if (tid < off) rbuf[tid] = fmaxf(rbuf[tid], rbuf[tid + off]);
    __syncthreads();
  }
  float mx = rbuf[0];
  __syncthreads();
  float e = __expf(s - mx);
  rbuf[tid] = e;
  __syncthreads();
  for (int off = 128; off > 0; off >>= 1) {
    if (tid < off) rbuf[tid] += rbuf[tid + off];
    __syncthreads();
  }
  out[(size_t)b * DOUT + tid] = e / rbuf[0];
}

// ---------------------------------------------------------------------------
extern "C" void kernel_launch(void* const* d_in, const int* in_sizes, int n_in,
                              void* d_out, int out_size, void* d_ws, size_t ws_size,
                              hipStream_t stream) {
  const float* x      = (const float*)d_in[0];
  const float* hidden = (const float*)d_in[1];
  const float* W_i2h  = (const float*)d_in[2];
  const float* b_i2h  = (const float*)d_in[3];
  const float* W_h2o  = (const float*)d_in[4];
  const float* b_h2o  = (const float*)d_in[5];
  float* out = (float*)d_out;

  char* ws = (char*)d_ws;
  ushort16* xw    = (ushort16*)(ws + XW_OFF);
  ushort16* Wh    = (ushort16*)(ws + WH_OFF);
  ushort16* Wx    = (ushort16*)(ws + WX_OFF);
  uint32*   hbuf  = (uint32*)(ws + HB_OFF);
  uint32*   flags = (uint32*)(ws + DN_OFF);

  prep_kernel<<<6144, 256, 0, stream>>>(W_i2h, hidden, Wx, Wh, hbuf, flags);
  xw_gemm_kernel<<<4096, 256, 0, stream>>>(x, Wx, xw);
  rnn_kernel<<<128, 256, 0, stream>>>(xw, Wh, b_i2h, hbuf, flags, out + BATCH * DOUT);
  head_kernel<<<128, 256, 0, stream>>>(out + BATCH * DOUT, W_h2o, b_h2o, out);
}